// Round 4
// baseline (203.264 us; speedup 1.0000x reference)
//
#include <hip/hip_runtime.h>
#include <math.h>

#define NRES 768
#define CDIM 384
#define HEADS 12
#define SCALE 0.17677669529663687f  // 1/sqrt(32)

typedef _Float16 f16;
typedef _Float16 __attribute__((ext_vector_type(8))) f16x8;
typedef float __attribute__((ext_vector_type(4))) f32x4;

// ---------------- prep: fp16 conversions, weight concat, Wcomb = Wo*Wpo, padding ----------------
__global__ __launch_bounds__(256) void prep_kernel(
    const float* __restrict__ Wq, const float* __restrict__ Wk, const float* __restrict__ Wv,
    const float* __restrict__ Wqp, const float* __restrict__ Wkp, const float* __restrict__ Wvp,
    const float* __restrict__ bq, const float* __restrict__ bk, const float* __restrict__ bv,
    const float* __restrict__ bqp, const float* __restrict__ bkp, const float* __restrict__ bvp,
    const float* __restrict__ single, const float* __restrict__ Wpo, const float* __restrict__ bpo,
    const float* __restrict__ Wo,
    f16* __restrict__ WcatH, float* __restrict__ bcatP, f16* __restrict__ singleH,
    f16* __restrict__ Bcat, f16* __restrict__ attn_cat) {
  int i = blockIdx.x * 256 + threadIdx.x;
  if (i < 614400) {  // WcatH [1600][384]
    int o = i / 384, c = i % 384;
    float v = 0.f;
    if (o < 384)       v = Wq[o * 384 + c];
    else if (o < 768)  v = Wk[(o - 384) * 384 + c];
    else if (o < 1152) v = Wv[(o - 768) * 384 + c];
    else if (o < 1296) v = Wqp[(o - 1152) * 384 + c];
    else if (o < 1440) v = Wkp[(o - 1296) * 384 + c];
    else if (o < 1584) v = Wvp[(o - 1440) * 384 + c];
    WcatH[i] = (f16)v;
    return;
  }
  i -= 614400;
  if (i < 1600) {  // bcatP [1600]
    float v = 0.f;
    if (i < 384)       v = bq[i];
    else if (i < 768)  v = bk[i - 384];
    else if (i < 1152) v = bv[i - 768];
    else if (i < 1296) v = bqp[i - 1152];
    else if (i < 1440) v = bkp[i - 1296];
    else if (i < 1584) v = bvp[i - 1440];
    bcatP[i] = v;
    return;
  }
  i -= 1600;
  if (i < 294912) { singleH[i] = (f16)single[i]; return; }
  i -= 294912;
  if (i < 147456) {  // Bcat cols 0..383 = Wo
    int o = i / 384, k = i % 384;
    Bcat[(size_t)o * 576 + k] = (f16)Wo[o * 384 + k];
    return;
  }
  i -= 147456;
  if (i < 384 * 145) {  // Wcomb[o][c] = sum_k Wo[o,k]*Wpo[k,c]; c==144 -> Wo*bpo
    int o = i / 145, c = i % 145;
    const float* wr = Wo + o * 384;
    float acc = 0.f;
    if (c < 144) {
#pragma unroll 4
      for (int k = 0; k < 384; ++k) acc += wr[k] * Wpo[k * 144 + c];
    } else {
#pragma unroll 4
      for (int k = 0; k < 384; ++k) acc += wr[k] * bpo[k];
    }
    Bcat[(size_t)o * 576 + 384 + c] = (f16)acc;
    return;
  }
  i -= 384 * 145;
  if (i < 384 * 47) {  // Bcat cols 529..575 = 0
    int o = i / 47, c = 529 + i % 47;
    Bcat[(size_t)o * 576 + c] = (f16)0.f;
    return;
  }
  i -= 384 * 47;
  if (i < 768 * 48) {  // attn_cat cols 528..575: 528 -> 1.0, rest 0
    int n = i / 48, c = 528 + i % 48;
    attn_cat[(size_t)n * 576 + c] = (f16)(c == 528 ? 1.f : 0.f);
  }
}

// ---------------- fp16 MFMA GEMM: C = A(MxK_h) * B(NdxK_h)^T + bias (+res) ----------------
__global__ __launch_bounds__(256) void gemm_mfma(
    const f16* __restrict__ A, const f16* __restrict__ B,
    const float* __restrict__ bias, const float* __restrict__ res,
    float* __restrict__ Cf, f16* __restrict__ Ch,
    int Nd, int K, int ldc) {
  __shared__ f16 As[64][64];
  __shared__ f16 Bs[64][64];
  const int t = threadIdx.x;
  const int w = t >> 6, l = t & 63;
  const int lg = l >> 4, lr = l & 15;
  const int bm = blockIdx.y * 64, bn = blockIdx.x * 64;
  f32x4 acc[4] = {{0.f,0.f,0.f,0.f},{0.f,0.f,0.f,0.f},{0.f,0.f,0.f,0.f},{0.f,0.f,0.f,0.f}};
  for (int k0 = 0; k0 < K; k0 += 64) {
    __syncthreads();
#pragma unroll
    for (int cc = 0; cc < 2; ++cc) {
      int c = t + cc * 256;
      int row = c >> 3, k8 = c & 7;
      int sw = (k8 ^ (row & 7)) * 8;
      *(f16x8*)&As[row][sw] = *(const f16x8*)(A + (size_t)(bm + row) * K + k0 + k8 * 8);
      *(f16x8*)&Bs[row][sw] = *(const f16x8*)(B + (size_t)(bn + row) * K + k0 + k8 * 8);
    }
    __syncthreads();
#pragma unroll
    for (int ks = 0; ks < 2; ++ks) {
      f16x8 af = *(const f16x8*)&As[w * 16 + lr][((ks * 4 + lg) ^ (lr & 7)) * 8];
#pragma unroll
      for (int c = 0; c < 4; ++c) {
        f16x8 bf = *(const f16x8*)&Bs[c * 16 + lr][((ks * 4 + lg) ^ (lr & 7)) * 8];
        acc[c] = __builtin_amdgcn_mfma_f32_16x16x32_f16(af, bf, acc[c], 0, 0, 0);
      }
    }
  }
#pragma unroll
  for (int c = 0; c < 4; ++c) {
    int col = bn + c * 16 + lr;
    if (col >= Nd) continue;
    float bv = bias[col];
#pragma unroll
    for (int r = 0; r < 4; ++r) {
      int row = bm + w * 16 + lg * 4 + r;
      float v = acc[c][r] + bv;
      if (res) v += res[(size_t)row * ldc + col];
      if (Cf) Cf[(size_t)row * ldc + col] = v;
      else    Ch[(size_t)row * ldc + col] = (f16)v;
    }
  }
}

// ---------------- rotate points, build packed fp16 features (from fp16 S) ----------------
__global__ __launch_bounds__(256) void rot_feats2(
    const f16* __restrict__ S16, const float* __restrict__ rot, const float* __restrict__ trans,
    f16* __restrict__ qf, f16* __restrict__ kf, f16* __restrict__ vfT) {
  const int n = blockIdx.x * 256 + threadIdx.x;
  const int h = blockIdx.y;
  const f16* Sr = S16 + (size_t)n * 1584;
  float R[9], T[3];
#pragma unroll
  for (int i = 0; i < 9; ++i) R[i] = rot[n * 9 + i];
#pragma unroll
  for (int i = 0; i < 3; ++i) T[i] = trans[n * 3 + i];
  f16 qh[64], kh[64];
  f16x8 qv4[4], kv4[4], vv4[4];
#pragma unroll
  for (int j = 0; j < 4; ++j) {
    qv4[j] = *(const f16x8*)(Sr + h * 32 + j * 8);
    kv4[j] = *(const f16x8*)(Sr + 384 + h * 32 + j * 8);
    vv4[j] = *(const f16x8*)(Sr + 768 + h * 32 + j * 8);
  }
#pragma unroll
  for (int c = 0; c < 32; ++c) {
    qh[c] = (f16)(SCALE * (float)qv4[c >> 3][c & 7]);
    kh[c] = kv4[c >> 3][c & 7];
    vfT[((size_t)(h * 48 + c)) * NRES + n] = vv4[c >> 3][c & 7];
  }
  float q2 = 0.f, k2 = 0.f;
  const f16* qp = Sr + 1152 + h * 12;
  const f16* kp = Sr + 1296 + h * 12;
  const f16* vp = Sr + 1440 + h * 12;
#pragma unroll
  for (int p = 0; p < 4; ++p) {
#pragma unroll
    for (int e = 0; e < 3; ++e) {
      float q0 = (float)qp[p * 3 + 0], q1 = (float)qp[p * 3 + 1], q2c = (float)qp[p * 3 + 2];
      float k0 = (float)kp[p * 3 + 0], k1 = (float)kp[p * 3 + 1], k2c = (float)kp[p * 3 + 2];
      float v0 = (float)vp[p * 3 + 0], v1 = (float)vp[p * 3 + 1], v2c = (float)vp[p * 3 + 2];
      float qg = q0 * R[e] + q1 * R[3 + e] + q2c * R[6 + e] + T[e];
      float kg = k0 * R[e] + k1 * R[3 + e] + k2c * R[6 + e] + T[e];
      float vg = v0 * R[e] + v1 * R[3 + e] + v2c * R[6 + e] + T[e];
      qh[32 + p * 3 + e] = (f16)(SCALE * qg); q2 += qg * qg;
      kh[32 + p * 3 + e] = (f16)kg;           k2 += kg * kg;
      vfT[((size_t)(h * 48 + 32 + p * 3 + e)) * NRES + n] = (f16)vg;
    }
  }
  qh[44] = (f16)(-0.5f * SCALE * q2); qh[45] = (f16)1.f;
  kh[44] = (f16)1.f;                  kh[45] = (f16)(-0.5f * SCALE * k2);
#pragma unroll
  for (int c = 46; c < 64; ++c) { qh[c] = (f16)0.f; kh[c] = (f16)0.f; }
#pragma unroll
  for (int c = 44; c < 48; ++c) vfT[((size_t)(h * 48 + c)) * NRES + n] = (f16)0.f;
  f16* qo = qf + ((size_t)(h * NRES + n)) * 64;
  f16* ko = kf + ((size_t)(h * NRES + n)) * 64;
#pragma unroll
  for (int j = 0; j < 8; ++j) {
    *(f16x8*)&qo[j * 8] = *(const f16x8*)&qh[j * 8];
    *(f16x8*)&ko[j * 8] = *(const f16x8*)&kh[j * 8];
  }
}

// ---------------- pair bias via MFMA ----------------
__global__ __launch_bounds__(256) void pair_bias_mfma(
    const float* __restrict__ pair, const float* __restrict__ Wpb,
    const float* __restrict__ bpb, f16* __restrict__ biasb) {
  const int t = threadIdx.x;
  const int w = t >> 6, l = t & 63;
  const int lg = l >> 4, lr = l & 15;
  f16x8 bfr[4];
#pragma unroll
  for (int ks = 0; ks < 4; ++ks)
#pragma unroll
    for (int j = 0; j < 8; ++j)
      bfr[ks][j] = (f16)((lr < HEADS) ? Wpb[lr * 128 + ks * 32 + lg * 8 + j] : 0.f);
  const float bh = (lr < HEADS) ? bpb[lr] : 0.f;
  const int gw = blockIdx.x * 4 + w;
#pragma unroll
  for (int tt = 0; tt < 4; ++tt) {
    const size_t row0 = ((size_t)gw * 4 + tt) * 16;
    f32x4 acc = {0.f, 0.f, 0.f, 0.f};
#pragma unroll
    for (int ks = 0; ks < 4; ++ks) {
      const float* ap = pair + (row0 + lr) * 128 + ks * 32 + lg * 8;
      f16x8 af;
#pragma unroll
      for (int j = 0; j < 8; ++j) af[j] = (f16)ap[j];
      acc = __builtin_amdgcn_mfma_f32_16x16x32_f16(af, bfr[ks], acc, 0, 0, 0);
    }
    if (lr < HEADS) {
#pragma unroll
      for (int r = 0; r < 4; ++r)
        biasb[(size_t)lr * (NRES * NRES) + row0 + lg * 4 + r] = (f16)(acc[r] + bh);
    }
  }
}

// ---------------- MFMA attention, no-max softmax, m-split over 8 waves ----------------
__global__ __launch_bounds__(512) void attn_mfma(
    const f16* __restrict__ qf, const f16* __restrict__ kf,
    const f16* __restrict__ vfT, const f16* __restrict__ biasb,
    f16* __restrict__ attn_cat) {
  __shared__ f16 plds[8][512];
  __shared__ float redO[8][16][48];
  __shared__ float redD[8][16];
  const int t = threadIdx.x;
  const int w = t >> 6, l = t & 63;
  const int lg = l >> 4, lr = l & 15;
  const int h = blockIdx.x, q0 = blockIdx.y * 16;

  const f16* qrow = qf + ((size_t)(h * NRES + q0 + lr)) * 64;
  f16x8 qa0 = *(const f16x8*)(qrow + lg * 8);
  f16x8 qa1 = *(const f16x8*)(qrow + 32 + lg * 8);

  f32x4 acc0 = {0.f, 0.f, 0.f, 0.f};
  f32x4 acc1 = {0.f, 0.f, 0.f, 0.f};
  f32x4 acc2 = {0.f, 0.f, 0.f, 0.f};
  float den[4] = {0.f, 0.f, 0.f, 0.f};

  for (int it = 0; it < 3; ++it) {
    const int m0 = w * 96 + it * 32;
#pragma unroll
    for (int ch = 0; ch < 2; ++ch) {
      const int mc = m0 + ch * 16;
      const f16* krow = kf + ((size_t)(h * NRES + mc + lr)) * 64;
      f16x8 kb0 = *(const f16x8*)(krow + lg * 8);
      f16x8 kb1 = *(const f16x8*)(krow + 32 + lg * 8);
      f32x4 s = {0.f, 0.f, 0.f, 0.f};
      s = __builtin_amdgcn_mfma_f32_16x16x32_f16(qa0, kb0, s, 0, 0, 0);
      s = __builtin_amdgcn_mfma_f32_16x16x32_f16(qa1, kb1, s, 0, 0, 0);
#pragma unroll
      for (int r = 0; r < 4; ++r) {
        float bias = (float)biasb[((size_t)(h * NRES + q0 + lg * 4 + r)) * NRES + mc + lr];
        float e = __expf(s[r] + bias);
        den[r] += e;
        plds[w][(lg * 4 + r) * 32 + ch * 16 + lr] = (f16)e;
      }
    }
    f16x8 pa = *(const f16x8*)(&plds[w][lr * 32 + lg * 8]);
    const f16* vbase = vfT + ((size_t)(h * 48 + lr)) * NRES + m0 + lg * 8;
    f16x8 vb0 = *(const f16x8*)(vbase);
    f16x8 vb1 = *(const f16x8*)(vbase + 16 * NRES);
    f16x8 vb2 = *(const f16x8*)(vbase + 32 * NRES);
    acc0 = __builtin_amdgcn_mfma_f32_16x16x32_f16(pa, vb0, acc0, 0, 0, 0);
    acc1 = __builtin_amdgcn_mfma_f32_16x16x32_f16(pa, vb1, acc1, 0, 0, 0);
    acc2 = __builtin_amdgcn_mfma_f32_16x16x32_f16(pa, vb2, acc2, 0, 0, 0);
  }
#pragma unroll
  for (int r = 0; r < 4; ++r) {
    float d = den[r];
    d += __shfl_xor(d, 1);
    d += __shfl_xor(d, 2);
    d += __shfl_xor(d, 4);
    d += __shfl_xor(d, 8);
    if (lr == 0) redD[w][lg * 4 + r] = d;
  }
#pragma unroll
  for (int r = 0; r < 4; ++r) {
    redO[w][lg * 4 + r][lr]      = acc0[r];
    redO[w][lg * 4 + r][16 + lr] = acc1[r];
    redO[w][lg * 4 + r][32 + lr] = acc2[r];
  }
  __syncthreads();
  for (int o = t; o < 16 * 48; o += 512) {
    int q = o / 48, c = o % 48;
    float num = 0.f, ds = 0.f;
#pragma unroll
    for (int ww = 0; ww < 8; ++ww) { num += redO[ww][q][c]; ds += redD[ww][q]; }
    float val = num / ds;
    int n = q0 + q;
    if (c < 32)      attn_cat[(size_t)n * 576 + h * 32 + c] = (f16)val;
    else if (c < 44) attn_cat[(size_t)n * 576 + 384 + h * 12 + (c - 32)] = (f16)val;
  }
}

// ---------------- layernorm ----------------
__global__ __launch_bounds__(64) void ln_kernel(
    const float* __restrict__ x, const float* __restrict__ w, const float* __restrict__ b,
    float* __restrict__ out) {
  int n = blockIdx.x;
  int l = threadIdx.x;
  const float* xr = x + (size_t)n * CDIM;
  float v[6];
  float s = 0.f;
#pragma unroll
  for (int i = 0; i < 6; ++i) { v[i] = xr[l + 64 * i]; s += v[i]; }
#pragma unroll
  for (int o = 32; o; o >>= 1) s += __shfl_xor(s, o);
  float mu = s * (1.f / 384.f);
  float vs = 0.f;
#pragma unroll
  for (int i = 0; i < 6; ++i) { float d = v[i] - mu; vs += d * d; }
#pragma unroll
  for (int o = 32; o; o >>= 1) vs += __shfl_xor(vs, o);
  float rstd = rsqrtf(vs * (1.f / 384.f) + 1e-5f);
  float* orow = out + (size_t)n * CDIM;
#pragma unroll
  for (int i = 0; i < 6; ++i) {
    int c = l + 64 * i;
    orow[c] = (v[i] - mu) * rstd * w[c] + b[c];
  }
}

extern "C" void kernel_launch(void* const* d_in, const int* in_sizes, int n_in,
                              void* d_out, int out_size, void* d_ws, size_t ws_size,
                              hipStream_t stream) {
  const float* single = (const float*)d_in[0];
  const float* pair   = (const float*)d_in[1];
  const float* rot    = (const float*)d_in[2];
  const float* trans  = (const float*)d_in[3];
  const float* Wq  = (const float*)d_in[4];
  const float* bq  = (const float*)d_in[5];
  const float* Wk  = (const float*)d_in[6];
  const float* bk  = (const float*)d_in[7];
  const float* Wv  = (const float*)d_in[8];
  const float* bv  = (const float*)d_in[9];
  const float* Wpb = (const float*)d_in[10];
  const float* bpb = (const float*)d_in[11];
  const float* Wqp = (const float*)d_in[12];
  const float* bqp = (const float*)d_in[13];
  const float* Wkp = (const float*)d_in[14];
  const float* bkp = (const float*)d_in[15];
  const float* Wvp = (const float*)d_in[16];
  const float* bvp = (const float*)d_in[17];
  const float* Wo  = (const float*)d_in[18];
  const float* bo  = (const float*)d_in[19];
  const float* Wpo = (const float*)d_in[20];
  const float* bpo = (const float*)d_in[21];
  const float* lnw = (const float*)d_in[22];
  const float* lnb = (const float*)d_in[23];

  float* ws = (float*)d_ws;
  f16* WcatH    = (f16*)ws; ws += 1600 * 384 / 2;
  float* bcatP  = ws;       ws += 1600;
  f16* singleH  = (f16*)ws; ws += 768 * 384 / 2;
  f16* Bcat     = (f16*)ws; ws += 384 * 576 / 2;
  f16* S16      = (f16*)ws; ws += 768 * 1584 / 2;
  f16* qf       = (f16*)ws; ws += 12 * 768 * 64 / 2;
  f16* kf       = (f16*)ws; ws += 12 * 768 * 64 / 2;
  f16* vfT      = (f16*)ws; ws += 12 * 48 * 768 / 2;
  f16* biasb    = (f16*)ws; ws += 12 * 768 * 768 / 2;
  f16* attn_cat = (f16*)ws; ws += 768 * 576 / 2;
  float* xb     = ws;       ws += 768 * 384;

  prep_kernel<<<4567, 256, 0, stream>>>(Wq, Wk, Wv, Wqp, Wkp, Wvp,
                                        bq, bk, bv, bqp, bkp, bvp,
                                        single, Wpo, bpo, Wo,
                                        WcatH, bcatP, singleH, Bcat, attn_cat);
  gemm_mfma<<<dim3(25, 12), 256, 0, stream>>>(singleH, WcatH, bcatP, nullptr,
                                              nullptr, S16, 1584, 384, 1584);
  rot_feats2<<<dim3(3, 12), 256, 0, stream>>>(S16, rot, trans, qf, kf, vfT);
  pair_bias_mfma<<<2304, 256, 0, stream>>>(pair, Wpb, bpb, biasb);
  attn_mfma<<<dim3(12, 48), 512, 0, stream>>>(qf, kf, vfT, biasb, attn_cat);
  gemm_mfma<<<dim3(6, 12), 256, 0, stream>>>(attn_cat, Bcat, bo, single,
                                             xb, nullptr, 384, 576, 384);
  ln_kernel<<<768, 64, 0, stream>>>(xb, lnw, lnb, (float*)d_out);
}

// Round 5
// 162.510 us; speedup vs baseline: 1.2508x; 1.2508x over previous
//
#include <hip/hip_runtime.h>
#include <math.h>

#define NRES 768
#define CDIM 384
#define HEADS 12
#define SCALE 0.17677669529663687f  // 1/sqrt(32)

typedef _Float16 f16;
typedef _Float16 __attribute__((ext_vector_type(8))) f16x8;
typedef float __attribute__((ext_vector_type(4))) f32x4;

// ---------------- prep: fp16 conversions, weight concat, padding (round-2 version) ----------------
__global__ __launch_bounds__(256) void prep_kernel(
    const float* __restrict__ Wq, const float* __restrict__ Wk, const float* __restrict__ Wv,
    const float* __restrict__ Wqp, const float* __restrict__ Wkp, const float* __restrict__ Wvp,
    const float* __restrict__ bq, const float* __restrict__ bk, const float* __restrict__ bv,
    const float* __restrict__ bqp, const float* __restrict__ bkp, const float* __restrict__ bvp,
    const float* __restrict__ single, const float* __restrict__ Wpo, const float* __restrict__ Wo,
    f16* __restrict__ WcatH, float* __restrict__ bcatP, f16* __restrict__ singleH,
    f16* __restrict__ WpoH, f16* __restrict__ WoH, f16* __restrict__ outpH) {
  int i = blockIdx.x * 256 + threadIdx.x;
  if (i < 614400) {  // WcatH [1600][384]
    int o = i / 384, c = i % 384;
    float v = 0.f;
    if (o < 384)       v = Wq[o * 384 + c];
    else if (o < 768)  v = Wk[(o - 384) * 384 + c];
    else if (o < 1152) v = Wv[(o - 768) * 384 + c];
    else if (o < 1296) v = Wqp[(o - 1152) * 384 + c];
    else if (o < 1440) v = Wkp[(o - 1296) * 384 + c];
    else if (o < 1584) v = Wvp[(o - 1440) * 384 + c];
    WcatH[i] = (f16)v;
    return;
  }
  i -= 614400;
  if (i < 1600) {
    float v = 0.f;
    if (i < 384)       v = bq[i];
    else if (i < 768)  v = bk[i - 384];
    else if (i < 1152) v = bv[i - 768];
    else if (i < 1296) v = bqp[i - 1152];
    else if (i < 1440) v = bkp[i - 1296];
    else if (i < 1584) v = bvp[i - 1440];
    bcatP[i] = v;
    return;
  }
  i -= 1600;
  if (i < 294912) { singleH[i] = (f16)single[i]; return; }
  i -= 294912;
  if (i < 73728) {  // WpoH [384][192], pad K 144->192
    int o = i / 192, c = i % 192;
    WpoH[i] = (f16)(c < 144 ? Wpo[o * 144 + c] : 0.f);
    return;
  }
  i -= 73728;
  if (i < 147456) { WoH[i] = (f16)Wo[i]; return; }
  i -= 147456;
  if (i < 36864) {  // outpH pad cols 144..191
    int n = i / 48, c = i % 48;
    outpH[n * 192 + 144 + c] = (f16)0.f;
  }
}

// ---------------- fp16 MFMA GEMM: C = A(MxK_h) * B(NdxK_h)^T + bias (+res) ----------------
__global__ __launch_bounds__(256) void gemm_mfma(
    const f16* __restrict__ A, const f16* __restrict__ B,
    const float* __restrict__ bias, const float* __restrict__ res,
    float* __restrict__ Cf, f16* __restrict__ Ch,
    int Nd, int K, int ldc) {
  __shared__ f16 As[64][64];
  __shared__ f16 Bs[64][64];
  const int t = threadIdx.x;
  const int w = t >> 6, l = t & 63;
  const int lg = l >> 4, lr = l & 15;
  const int bm = blockIdx.y * 64, bn = blockIdx.x * 64;
  f32x4 acc[4] = {{0.f,0.f,0.f,0.f},{0.f,0.f,0.f,0.f},{0.f,0.f,0.f,0.f},{0.f,0.f,0.f,0.f}};
  for (int k0 = 0; k0 < K; k0 += 64) {
    __syncthreads();
#pragma unroll
    for (int cc = 0; cc < 2; ++cc) {
      int c = t + cc * 256;
      int row = c >> 3, k8 = c & 7;
      int sw = (k8 ^ (row & 7)) * 8;
      *(f16x8*)&As[row][sw] = *(const f16x8*)(A + (size_t)(bm + row) * K + k0 + k8 * 8);
      *(f16x8*)&Bs[row][sw] = *(const f16x8*)(B + (size_t)(bn + row) * K + k0 + k8 * 8);
    }
    __syncthreads();
#pragma unroll
    for (int ks = 0; ks < 2; ++ks) {
      f16x8 af = *(const f16x8*)&As[w * 16 + lr][((ks * 4 + lg) ^ (lr & 7)) * 8];
#pragma unroll
      for (int c = 0; c < 4; ++c) {
        f16x8 bf = *(const f16x8*)&Bs[c * 16 + lr][((ks * 4 + lg) ^ (lr & 7)) * 8];
        acc[c] = __builtin_amdgcn_mfma_f32_16x16x32_f16(af, bf, acc[c], 0, 0, 0);
      }
    }
  }
#pragma unroll
  for (int c = 0; c < 4; ++c) {
    int col = bn + c * 16 + lr;
    if (col >= Nd) continue;
    float bv = bias[col];
#pragma unroll
    for (int r = 0; r < 4; ++r) {
      int row = bm + w * 16 + lg * 4 + r;
      float v = acc[c][r] + bv;
      if (res) v += res[(size_t)row * ldc + col];
      if (Cf) Cf[(size_t)row * ldc + col] = v;
      else    Ch[(size_t)row * ldc + col] = (f16)v;
    }
  }
}

// ---------------- rotate points, build packed fp16 features (round-2 version, fp32 S) ----------------
__global__ __launch_bounds__(256) void rot_feats2(
    const float* __restrict__ S, const float* __restrict__ rot, const float* __restrict__ trans,
    f16* __restrict__ qf, f16* __restrict__ kf, f16* __restrict__ vfT) {
  const int n = blockIdx.x * 256 + threadIdx.x;
  const int h = blockIdx.y;
  const float* Sr = S + (size_t)n * 1584;
  float R[9], T[3];
#pragma unroll
  for (int i = 0; i < 9; ++i) R[i] = rot[n * 9 + i];
#pragma unroll
  for (int i = 0; i < 3; ++i) T[i] = trans[n * 3 + i];
  float qv[64], kv[64];
#pragma unroll
  for (int c = 0; c < 32; ++c) {
    qv[c] = SCALE * Sr[h * 32 + c];
    kv[c] = Sr[384 + h * 32 + c];
    vfT[((size_t)(h * 48 + c)) * NRES + n] = (f16)Sr[768 + h * 32 + c];
  }
  float q2 = 0.f, k2 = 0.f;
#pragma unroll
  for (int p = 0; p < 4; ++p) {
    const float* qp = Sr + 1152 + (h * 4 + p) * 3;
    const float* kp = Sr + 1296 + (h * 4 + p) * 3;
    const float* vp = Sr + 1440 + (h * 4 + p) * 3;
#pragma unroll
    for (int e = 0; e < 3; ++e) {
      float qg = qp[0] * R[e] + qp[1] * R[3 + e] + qp[2] * R[6 + e] + T[e];
      float kg = kp[0] * R[e] + kp[1] * R[3 + e] + kp[2] * R[6 + e] + T[e];
      float vg = vp[0] * R[e] + vp[1] * R[3 + e] + vp[2] * R[6 + e] + T[e];
      qv[32 + p * 3 + e] = SCALE * qg; q2 += qg * qg;
      kv[32 + p * 3 + e] = kg;         k2 += kg * kg;
      vfT[((size_t)(h * 48 + 32 + p * 3 + e)) * NRES + n] = (f16)vg;
    }
  }
  qv[44] = -0.5f * SCALE * q2; qv[45] = 1.f;
  kv[44] = 1.f;                kv[45] = -0.5f * SCALE * k2;
#pragma unroll
  for (int c = 46; c < 64; ++c) { qv[c] = 0.f; kv[c] = 0.f; }
#pragma unroll
  for (int c = 44; c < 48; ++c) vfT[((size_t)(h * 48 + c)) * NRES + n] = (f16)0.f;
  f16* qo = qf + ((size_t)(h * NRES + n)) * 64;
  f16* ko = kf + ((size_t)(h * NRES + n)) * 64;
#pragma unroll
  for (int c = 0; c < 64; ++c) { qo[c] = (f16)qv[c]; ko[c] = (f16)kv[c]; }
}

// ---------------- fused pair-bias + attention ----------------
// grid (12 m-chunks, 48 q-tiles) x 512 thr. Each block: pair[q0:q0+16][m0:m0+64][:]
// phase1: bias for all 12 heads via MFMA (K=128) -> LDS
// phase2: per-head QK+exp+PV partials over m-chunk -> partN/partD
__global__ __launch_bounds__(512) void fused_attn(
    const float* __restrict__ pair, const float* __restrict__ Wpb, const float* __restrict__ bpb,
    const f16* __restrict__ qf, const f16* __restrict__ kf, const f16* __restrict__ vfT,
    float* __restrict__ partN, float* __restrict__ partD) {
  __shared__ f16 bias_l[12 * 1160];   // head stride 1160, row stride 72 (padded)
  __shared__ f16 p_l[8][1160];        // per-wave P tile, row stride 72
  const int t = threadIdx.x;
  const int w = t >> 6, l = t & 63;
  const int lg = l >> 4, lr = l & 15;
  const int mblk = blockIdx.x;
  const int q0 = blockIdx.y * 16;
  const int m0 = mblk * 64;

  // Wpb B-fragments (col = head)
  f16x8 bfr[4];
#pragma unroll
  for (int ks = 0; ks < 4; ++ks)
#pragma unroll
    for (int j = 0; j < 8; ++j)
      bfr[ks][j] = (f16)((lr < HEADS) ? Wpb[lr * 128 + ks * 32 + lg * 8 + j] : 0.f);
  const float bh = (lr < HEADS) ? bpb[lr] : 0.f;

  // ---- phase 1: bias tile (1024 (n,m)-rows x 12 heads), 8 groups per wave ----
#pragma unroll
  for (int g8 = 0; g8 < 8; ++g8) {
    const int g = w * 8 + g8;
    const int rowf = g * 16 + lr;            // A-frag row: flat (n_l*64 + m_l)
    const int nf = rowf >> 6, mf = rowf & 63;
    const float* ap = pair + (((size_t)(q0 + nf)) * NRES + (m0 + mf)) * 128 + lg * 8;
    f32x4 acc = {0.f, 0.f, 0.f, 0.f};
#pragma unroll
    for (int ks = 0; ks < 4; ++ks) {
      float4 a0 = *(const float4*)(ap + ks * 32);
      float4 a1 = *(const float4*)(ap + ks * 32 + 4);
      f16x8 af = {(f16)a0.x, (f16)a0.y, (f16)a0.z, (f16)a0.w,
                  (f16)a1.x, (f16)a1.y, (f16)a1.z, (f16)a1.w};
      acc = __builtin_amdgcn_mfma_f32_16x16x32_f16(af, bfr[ks], acc, 0, 0, 0);
    }
    if (lr < HEADS) {
#pragma unroll
      for (int r = 0; r < 4; ++r) {
        int rowo = g * 16 + lg * 4 + r;
        bias_l[lr * 1160 + (rowo >> 6) * 72 + (rowo & 63)] = (f16)(acc[r] + bh);
      }
    }
  }
  __syncthreads();

  // ---- phase 2: per-head attention partials ----
  for (int h = w; h < 12; h += 8) {
    const f16* qrow = qf + ((size_t)(h * NRES + q0 + lr)) * 64;
    f16x8 qa0 = *(const f16x8*)(qrow + lg * 8);
    f16x8 qa1 = *(const f16x8*)(qrow + 32 + lg * 8);
    float den[4] = {0.f, 0.f, 0.f, 0.f};
#pragma unroll
    for (int mc = 0; mc < 4; ++mc) {
      const f16* krow = kf + ((size_t)(h * NRES + m0 + mc * 16 + lr)) * 64;
      f16x8 kb0 = *(const f16x8*)(krow + lg * 8);
      f16x8 kb1 = *(const f16x8*)(krow + 32 + lg * 8);
      f32x4 s = {0.f, 0.f, 0.f, 0.f};
      s = __builtin_amdgcn_mfma_f32_16x16x32_f16(qa0, kb0, s, 0, 0, 0);
      s = __builtin_amdgcn_mfma_f32_16x16x32_f16(qa1, kb1, s, 0, 0, 0);
#pragma unroll
      for (int r = 0; r < 4; ++r) {
        float b = (float)bias_l[h * 1160 + (lg * 4 + r) * 72 + mc * 16 + lr];
        float e = __expf(s[r] + b);   // bounded logits: no max needed
        den[r] += e;
        p_l[w][(lg * 4 + r) * 72 + mc * 16 + lr] = (f16)e;
      }
    }
#pragma unroll
    for (int r = 0; r < 4; ++r) {
      float d = den[r];
      d += __shfl_xor(d, 1); d += __shfl_xor(d, 2);
      d += __shfl_xor(d, 4); d += __shfl_xor(d, 8);
      if (lr == 0)
        partD[((size_t)mblk * NRES + q0 + lg * 4 + r) * 12 + h] = d;
    }
#pragma unroll
    for (int c3 = 0; c3 < 3; ++c3) {
      f32x4 a = {0.f, 0.f, 0.f, 0.f};
#pragma unroll
      for (int ks = 0; ks < 2; ++ks) {
        f16x8 pa = *(const f16x8*)&p_l[w][lr * 72 + ks * 32 + lg * 8];
        f16x8 vb = *(const f16x8*)(vfT + ((size_t)(h * 48 + c3 * 16 + lr)) * NRES + m0 + ks * 32 + lg * 8);
        a = __builtin_amdgcn_mfma_f32_16x16x32_f16(pa, vb, a, 0, 0, 0);
      }
#pragma unroll
      for (int r = 0; r < 4; ++r)
        partN[((size_t)mblk * NRES + q0 + lg * 4 + r) * 576 + h * 48 + c3 * 16 + lr] = a[r];
    }
  }
}

// ---------------- reduce partials over 12 m-chunks, normalize ----------------
__global__ __launch_bounds__(576) void attn_reduce(
    const float* __restrict__ partN, const float* __restrict__ partD,
    float* __restrict__ outs, f16* __restrict__ outpH) {
  const int n = blockIdx.x;
  const int hc = threadIdx.x;     // 0..575
  const int h = hc / 48, c = hc - h * 48;
  float num = 0.f, den = 0.f;
#pragma unroll
  for (int mc = 0; mc < 12; ++mc) {
    num += partN[((size_t)mc * NRES + n) * 576 + hc];
    den += partD[((size_t)mc * NRES + n) * 12 + h];
  }
  float val = num / den;
  if (c < 32)      outs[(size_t)n * 384 + h * 32 + c] = val;
  else if (c < 44) outpH[(size_t)n * 192 + h * 12 + (c - 32)] = (f16)val;
}

// ---------------- layernorm ----------------
__global__ __launch_bounds__(64) void ln_kernel(
    const float* __restrict__ x, const float* __restrict__ w, const float* __restrict__ b,
    float* __restrict__ out) {
  int n = blockIdx.x;
  int l = threadIdx.x;
  const float* xr = x + (size_t)n * CDIM;
  float v[6];
  float s = 0.f;
#pragma unroll
  for (int i = 0; i < 6; ++i) { v[i] = xr[l + 64 * i]; s += v[i]; }
#pragma unroll
  for (int o = 32; o; o >>= 1) s += __shfl_xor(s, o);
  float mu = s * (1.f / 384.f);
  float vs = 0.f;
#pragma unroll
  for (int i = 0; i < 6; ++i) { float d = v[i] - mu; vs += d * d; }
#pragma unroll
  for (int o = 32; o; o >>= 1) vs += __shfl_xor(vs, o);
  float rstd = rsqrtf(vs * (1.f / 384.f) + 1e-5f);
  float* orow = out + (size_t)n * CDIM;
#pragma unroll
  for (int i = 0; i < 6; ++i) {
    int c = l + 64 * i;
    orow[c] = (v[i] - mu) * rstd * w[c] + b[c];
  }
}

extern "C" void kernel_launch(void* const* d_in, const int* in_sizes, int n_in,
                              void* d_out, int out_size, void* d_ws, size_t ws_size,
                              hipStream_t stream) {
  const float* single = (const float*)d_in[0];
  const float* pair   = (const float*)d_in[1];
  const float* rot    = (const float*)d_in[2];
  const float* trans  = (const float*)d_in[3];
  const float* Wq  = (const float*)d_in[4];
  const float* bq  = (const float*)d_in[5];
  const float* Wk  = (const float*)d_in[6];
  const float* bk  = (const float*)d_in[7];
  const float* Wv  = (const float*)d_in[8];
  const float* bv  = (const float*)d_in[9];
  const float* Wpb = (const float*)d_in[10];
  const float* bpb = (const float*)d_in[11];
  const float* Wqp = (const float*)d_in[12];
  const float* bqp = (const float*)d_in[13];
  const float* Wkp = (const float*)d_in[14];
  const float* bkp = (const float*)d_in[15];
  const float* Wvp = (const float*)d_in[16];
  const float* bvp = (const float*)d_in[17];
  const float* Wo  = (const float*)d_in[18];
  const float* bo  = (const float*)d_in[19];
  const float* Wpo = (const float*)d_in[20];
  const float* bpo = (const float*)d_in[21];
  const float* lnw = (const float*)d_in[22];
  const float* lnb = (const float*)d_in[23];

  float* ws = (float*)d_ws;
  f16* WcatH   = (f16*)ws; ws += 1600 * 384 / 2;
  float* bcatP = ws;       ws += 1600;
  f16* singleH = (f16*)ws; ws += 768 * 384 / 2;
  f16* WpoH    = (f16*)ws; ws += 384 * 192 / 2;
  f16* WoH     = (f16*)ws; ws += 384 * 384 / 2;
  float* S     = ws;       ws += 768 * 1584;
  f16* qf      = (f16*)ws; ws += 12 * 768 * 64 / 2;
  f16* kf      = (f16*)ws; ws += 12 * 768 * 64 / 2;
  f16* vfT     = (f16*)ws; ws += 12 * 48 * 768 / 2;
  float* partN = ws;       ws += 12 * 768 * 576;
  float* partD = ws;       ws += 12 * 768 * 12;
  float* outs  = ws;       ws += 768 * 384;
  f16* outpH   = (f16*)ws; ws += 768 * 192 / 2;
  f16* u_h     = (f16*)ws; ws += 768 * 384 / 2;
  float* xb    = ws;       ws += 768 * 384;

  prep_kernel<<<4567, 256, 0, stream>>>(Wq, Wk, Wv, Wqp, Wkp, Wvp,
                                        bq, bk, bv, bqp, bkp, bvp,
                                        single, Wpo, Wo,
                                        WcatH, bcatP, singleH, WpoH, WoH, outpH);
  gemm_mfma<<<dim3(25, 12), 256, 0, stream>>>(singleH, WcatH, bcatP, nullptr,
                                              S, nullptr, 1584, 384, 1584);
  rot_feats2<<<dim3(3, 12), 256, 0, stream>>>(S, rot, trans, qf, kf, vfT);
  fused_attn<<<dim3(12, 48), 512, 0, stream>>>(pair, Wpb, bpb, qf, kf, vfT, partN, partD);
  attn_reduce<<<768, 576, 0, stream>>>(partN, partD, outs, outpH);
  gemm_mfma<<<dim3(6, 12), 256, 0, stream>>>(outpH, WpoH, bpo, outs, nullptr, u_h, 384, 192, 384);
  gemm_mfma<<<dim3(6, 12), 256, 0, stream>>>(u_h, WoH, bo, single, xb, nullptr, 384, 384, 384);
  ln_kernel<<<768, 64, 0, stream>>>(xb, lnw, lnb, (float*)d_out);
}